// Round 10
// baseline (6065.076 us; speedup 1.0000x reference)
//
#include <hip/hip_runtime.h>
#include <cstdint>
#include <cstddef>

#define H_DIM 2560
#define I_DIM 6912
#define NTOK  8192   // B*S = 4*2048

typedef __attribute__((ext_vector_type(8))) __bf16 bf16x8;
typedef __attribute__((ext_vector_type(4))) float  f32x4;

// ---- async global->LDS, 16B per lane -------------------------------------
__device__ inline void gld16(void* lds, const void* g) {
    __builtin_amdgcn_global_load_lds(
        (__attribute__((address_space(1))) void*)(void*)g,
        (__attribute__((address_space(3))) void*)lds, 16, 0, 0);
}

// ---- merged prep: cvt_x | unpack gate+up | unpack down --------------------
#define NB_CVT 10240   // NTOK*H/8/256
#define NB_GU  17280   // 2*I*H/8/256
#define NB_WD  8640    // H*I/8/256

__global__ __launch_bounds__(256) void prep_kernel(
    const float* __restrict__ x, __bf16* __restrict__ xb,
    const int* __restrict__ gp, const int* __restrict__ up, __bf16* __restrict__ bgu,
    const int* __restrict__ dp, const float* __restrict__ nw, __bf16* __restrict__ wdb)
{
    const int bid = blockIdx.x;
    if (bid < NB_CVT) {
        int gid = bid * 256 + threadIdx.x;
        const float4* p = (const float4*)(x + (size_t)gid * 8);
        float4 v0 = p[0], v1 = p[1];
        bf16x8 o;
        o[0] = (__bf16)v0.x; o[1] = (__bf16)v0.y; o[2] = (__bf16)v0.z; o[3] = (__bf16)v0.w;
        o[4] = (__bf16)v1.x; o[5] = (__bf16)v1.y; o[6] = (__bf16)v1.z; o[7] = (__bf16)v1.w;
        *(bf16x8*)(xb + (size_t)gid * 8) = o;
    } else if (bid < NB_CVT + NB_GU) {
        const int per_row = H_DIM >> 3;
        const int half = I_DIM * per_row;
        int gid = (bid - NB_CVT) * 256 + threadIdx.x;
        const bool isup = gid >= half;
        const int g = isup ? gid - half : gid;
        const int* packed = isup ? up : gp;
        int i  = g / per_row;
        int k0 = (g % per_row) * 8;
        int blk = k0 >> 7, grp = (k0 >> 5) & 3, j0 = k0 & 31;
        int shift = 6 - 2 * grp;
        const int* p = packed + (size_t)i * (H_DIM >> 2) + blk * 32 + j0;
        int4 v0 = *(const int4*)p;
        int4 v1 = *(const int4*)(p + 4);
        int vals[8] = {v0.x, v0.y, v0.z, v0.w, v1.x, v1.y, v1.z, v1.w};
        bf16x8 o;
#pragma unroll
        for (int b = 0; b < 8; ++b)
            o[b] = (__bf16)(float)(((vals[b] >> shift) & 3) - 1);
        int dst = (i >> 4) * 32 + (i & 15) + (isup ? 16 : 0);
        *(bf16x8*)(bgu + (size_t)dst * H_DIM + k0) = o;
    } else {
        const int per_row = I_DIM >> 3;
        int gid = (bid - NB_CVT - NB_GU) * 256 + threadIdx.x;
        int i  = gid / per_row;
        int k0 = (gid % per_row) * 8;
        int blk = k0 >> 7, grp = (k0 >> 5) & 3, j0 = k0 & 31;
        int shift = 6 - 2 * grp;
        const int* p = dp + (size_t)i * (I_DIM >> 2) + blk * 32 + j0;
        int4 v0 = *(const int4*)p;
        int4 v1 = *(const int4*)(p + 4);
        int vals[8] = {v0.x, v0.y, v0.z, v0.w, v1.x, v1.y, v1.z, v1.w};
        bf16x8 o;
#pragma unroll
        for (int b = 0; b < 8; ++b) {
            float f = (float)(((vals[b] >> shift) & 3) - 1);
            o[b] = (__bf16)(f * nw[k0 + b]);
        }
        *(bf16x8*)(wdb + (size_t)i * I_DIM + k0) = o;
    }
}

// ---- per-token rsqrt(mean(hidden^2)+eps) ----------------------------------
__global__ __launch_bounds__(256) void rms_rs_kernel(const __bf16* __restrict__ hidden,
                                                     float* __restrict__ rs) {
    const int tk = blockIdx.x;
    const __bf16* row = hidden + (size_t)tk * I_DIM;
    float s = 0.f;
    for (int idx = threadIdx.x; idx < I_DIM / 8; idx += 256) {
        bf16x8 v = *(const bf16x8*)&row[idx * 8];
#pragma unroll
        for (int j = 0; j < 8; ++j) { float f = (float)v[j]; s += f * f; }
    }
#pragma unroll
    for (int off = 32; off; off >>= 1) s += __shfl_down(s, off, 64);
    __shared__ float wsum[4];
    if ((threadIdx.x & 63) == 0) wsum[threadIdx.x >> 6] = s;
    __syncthreads();
    if (threadIdx.x == 0) {
        float tot = wsum[0] + wsum[1] + wsum[2] + wsum[3];
        rs[tk] = rsqrtf(tot / (float)I_DIM + 1e-6f);
    }
}

// ===========================================================================
// R10 gate+up GEMM: BM=BN=256, BK=32, LDS 64 KiB -> 2 blocks/CU (4 waves/
// SIMD). 2 phases/tile {nh0, nh1}; A+B stored as row-pair 128B lines with the
// R4-proven XOR swizzle (0 conflicts). Depth-2 prefetch, counted vmcnt(2).
// Ledger: A of buffer d freed at kt.P1 -> stage kt+2.A in kt.P2;
//         B freed at kt.P2 -> stage kt+1.B in kt.P1 (buffer d^1, freed at
//         (kt-1).P2, confirmed by the barrier preceding kt.P1).
// vmcnt(2) at kt.P2 drains kt+1.{A,B} (issue order: kt+1.A @ (kt-1).P2,
// kt+1.B @ kt.P1, kt+2.A @ kt.P2 -> keep newest 2 = kt+2.A only).
// ===========================================================================
template<int KDIM>
__global__ __launch_bounds__(512, 4) void gemm_gu8(
    const __bf16* __restrict__ A,
    const __bf16* __restrict__ B,
    const float* __restrict__ gs_p,
    const float* __restrict__ us_p,
    __bf16* __restrict__ hidden,
    int nby)
{
    constexpr int KB = KDIM * 2;
    constexpr int NT = KDIM / 32;
    __shared__ __align__(16) char smem[65536];   // 2 buf x {A 16KB | B 16KB}

    const int nwg = (int)gridDim.x;
    const int q = nwg >> 3;
    const int id = (int)blockIdx.x;
    const int wg = (id & 7) * q + (id >> 3);
    const int bx = wg / nby, by = wg % nby;
    const int m0 = bx * 256, n0 = by * 256;

    const int t = (int)threadIdx.x;
    const int lane = t & 63;
    const int wid = t >> 6;
    const int wm = wid >> 2, wn = wid & 3;
    const int l15 = lane & 15, s8 = lane >> 4;

    // staging: inverse-swizzled global source, linear LDS dest (t*16).
    // dest line = t>>3 (128B row-pair), sub' = t&7; logical qa = sub'^(line&7)
    const int qa  = (t & 7) ^ ((t >> 3) & 7);
    const int rA2 = ((t >> 3) << 1) + (qa >> 2);   // row within 128-row group
    const int cb  = (qa & 3) * 16;                 // 16B K-sub within 64B row
    const char* gA0 = (const char*)A + (size_t)(m0 + rA2) * KB + cb;
    const char* gA1 = (const char*)A + (size_t)(m0 + 128 + rA2) * KB + cb;
    const char* gBp0 = (const char*)B + (size_t)(n0 + rA2) * KB + cb;
    const char* gBp1 = (const char*)B + (size_t)(n0 + 128 + rA2) * KB + cb;
    char* ldst = smem + t * 16;

    // compute-side swizzled read offsets (R4-proven conflict-free pattern)
    const int rswz  = ((((l15 & 1) << 2) | s8) ^ ((l15 >> 1) & 7)) << 4;
    const int abase = (wm * 64 + (l15 >> 1)) * 128 + rswz;   // + f*1024
    const int bbase = (wn * 32 + (l15 >> 1)) * 128 + rswz;   // + nh*2048, +1024

    f32x4 acc[8][4];
#pragma unroll
    for (int f = 0; f < 8; ++f)
#pragma unroll
        for (int n = 0; n < 4; ++n) acc[f][n] = (f32x4){0, 0, 0, 0};

#define STG_A(d, kt) do {                                                  \
        gld16(ldst + (d) * 32768,        gA0 + (size_t)(kt) * 64);         \
        gld16(ldst + (d) * 32768 + 8192, gA1 + (size_t)(kt) * 64);         \
    } while (0)
#define STG_B(d, kt) do {                                                  \
        gld16(ldst + (d) * 32768 + 16384,        gBp0 + (size_t)(kt) * 64);\
        gld16(ldst + (d) * 32768 + 16384 + 8192, gBp1 + (size_t)(kt) * 64);\
    } while (0)
#define LOAD_A(d) do { _Pragma("unroll")                                   \
        for (int _f = 0; _f < 8; ++_f)                                     \
            a[_f] = *(const bf16x8*)(smem + (d) * 32768 +                  \
                                     _f * 1024 + abase); } while (0)
#define LOAD_B(d, nh) do {                                                 \
        b0 = *(const bf16x8*)(smem + (d) * 32768 + 16384 + (nh) * 2048 +   \
                              bbase);                                      \
        b1 = *(const bf16x8*)(smem + (d) * 32768 + 16384 + (nh) * 2048 +   \
                              bbase + 1024); } while (0)
#define MFMA16(nh) do { __builtin_amdgcn_s_setprio(1); _Pragma("unroll")   \
        for (int _f = 0; _f < 8; ++_f) {                                   \
            acc[_f][(nh) * 2] = __builtin_amdgcn_mfma_f32_16x16x32_bf16(   \
                a[_f], b0, acc[_f][(nh) * 2], 0, 0, 0);                    \
            acc[_f][(nh) * 2 + 1] = __builtin_amdgcn_mfma_f32_16x16x32_bf16(\
                a[_f], b1, acc[_f][(nh) * 2 + 1], 0, 0, 0); }              \
        __builtin_amdgcn_s_setprio(0); } while (0)
#define BAR() do { asm volatile("" ::: "memory");                          \
        __builtin_amdgcn_s_barrier();                                      \
        asm volatile("" ::: "memory"); } while (0)

    // prologue: tile0 {A,B} + tile1 {A}; drain tile0 (keep tile1.A in flight)
    STG_A(0, 0); STG_B(0, 0); STG_A(1, 1);
    asm volatile("s_waitcnt vmcnt(2)" ::: "memory");
    BAR();

    bf16x8 a[8], b0, b1;
    for (int kt = 0; kt < NT; ++kt) {
        const int d = kt & 1;
        // P1 (nh0): a-frags + b(nh0); stage (kt+1).B into d^1
        LOAD_A(d); LOAD_B(d, 0);
        if (kt + 1 < NT) STG_B(d ^ 1, kt + 1);
        MFMA16(0); BAR();
        // P2 (nh1): b(nh1); stage (kt+2).A into d; counted tile-boundary wait
        LOAD_B(d, 1);
        if (kt + 2 < NT) {
            STG_A(d, kt + 2);
            asm volatile("s_waitcnt vmcnt(2)" ::: "memory");
        } else if (kt + 1 < NT) {
            asm volatile("s_waitcnt vmcnt(0)" ::: "memory");
        }
        MFMA16(1); BAR();
    }

#undef STG_A
#undef STG_B
#undef LOAD_A
#undef LOAD_B
#undef MFMA16
#undef BAR

    const float comb = gs_p[0] * gs_p[0] * us_p[0];
    const int r0 = m0 + wm * 128 + s8 * 4;
#pragma unroll
    for (int f = 0; f < 8; ++f)
#pragma unroll
        for (int p = 0; p < 2; ++p)
#pragma unroll
            for (int j = 0; j < 4; ++j) {
                float g = acc[f][2 * p][j];
                float u = acc[f][2 * p + 1][j];
                float r = fmaxf(g, 0.f);
                hidden[(size_t)(r0 + f * 16 + j) * I_DIM +
                       ((by * 8 + wn * 2 + p) * 16 + l15)] = (__bf16)(comb * r * r * u);
            }
}

// ===========================================================================
// Down GEMM (R8-proven): BM=256, BN=160, BK=64, grid 512 = 2 exact rounds,
// triple-buffer depth-2, vmcnt(6), T2 swizzle, T5 setprio.
// ===========================================================================
template<int KDIM>
__global__ __launch_bounds__(512) void gemm_down_pipe(
    const __bf16* __restrict__ A,
    const __bf16* __restrict__ B,
    const float* __restrict__ ds_p,
    const float* __restrict__ rs,
    float* __restrict__ outf,
    int nby)
{
    constexpr int BM = 256, BN = 160, BK = 64;
    constexpr int NT = KDIM / BK;
    constexpr int SLOTB = (BM + BN) * BK * 2;
    __shared__ __align__(16) char smem[3 * SLOTB];

    const int nwg = (int)gridDim.x;
    const int q = nwg >> 3;
    const int id = (int)blockIdx.x;
    const int wg = (id & 7) * q + (id >> 3);
    const int bx = wg / nby;
    const int by = wg % nby;

    const int m0 = bx * BM;
    const int n0 = by * BN;
    const int t  = (int)threadIdx.x;
    const int lane = t & 63;
    const int wm = (t >> 6) >> 1;
    const int wn = (t >> 6) & 1;

    const int srow = t >> 3;
    const int scol = ((t & 7) * 16) ^ ((srow & 7) << 4);
    const char* gA = (const char*)A + (size_t)(m0 + srow) * (KDIM * 2) + scol;
    const char* gB = (const char*)B + (size_t)(n0 + srow) * (KDIM * 2) + scol;
    char* lbase = smem + t * 16;

    const int l15 = lane & 15;
    const int xv  = (l15 & 7) << 4;
    const int colx[2] = { (((lane >> 4) * 16) ^ xv), ((64 + (lane >> 4) * 16) ^ xv) };

    f32x4 acc[4][5];
#pragma unroll
    for (int a = 0; a < 4; ++a)
#pragma unroll
        for (int b = 0; b < 5; ++b) acc[a][b] = (f32x4){0, 0, 0, 0};

#define STAGE_T(s, kt) do {                                                     \
        char* _ls = lbase + (s) * SLOTB;                                        \
        const char* _ga = gA + (kt) * (BK * 2);                                 \
        _Pragma("unroll")                                                       \
        for (int _i = 0; _i < 4; ++_i)                                          \
            gld16(_ls + _i * 8192, _ga + (size_t)_i * 64 * (KDIM * 2));         \
        const char* _gb = gB + (kt) * (BK * 2);                                 \
        char* _lb = _ls + BM * BK * 2;                                          \
        _Pragma("unroll")                                                       \
        for (int _i = 0; _i < 2; ++_i)                                          \
            gld16(_lb + _i * 8192, _gb + (size_t)_i * 64 * (KDIM * 2));         \
        if (t < 256)                                                            \
            gld16(_lb + 2 * 8192, _gb + (size_t)2 * 64 * (KDIM * 2));           \
    } while (0)

#define COMPUTE_T(s) do {                                                       \
        const char* _sa = smem + (s) * SLOTB;                                   \
        const char* _sb = _sa + BM * BK * 2;                                    \
        _Pragma("unroll")                                                       \
        for (int _kk = 0; _kk < 2; ++_kk) {                                     \
            bf16x8 _a[4], _b[5];                                                \
            _Pragma("unroll")                                                   \
            for (int _f = 0; _f < 4; ++_f)                                      \
                _a[_f] = *(const bf16x8*)(_sa + (wm * 64 + _f * 16 + l15) * 128 + colx[_kk]); \
            _Pragma("unroll")                                                   \
            for (int _f = 0; _f < 5; ++_f)                                      \
                _b[_f] = *(const bf16x8*)(_sb + (wn * 80 + _f * 16 + l15) * 128 + colx[_kk]); \
            __builtin_amdgcn_s_setprio(1);                                      \
            _Pragma("unroll")                                                   \
            for (int _fm = 0; _fm < 4; ++_fm)                                   \
                _Pragma("unroll")                                               \
                for (int _fn = 0; _fn < 5; ++_fn)                               \
                    acc[_fm][_fn] = __builtin_amdgcn_mfma_f32_16x16x32_bf16(    \
                        _a[_fm], _b[_fn], acc[_fm][_fn], 0, 0, 0);              \
            __builtin_amdgcn_s_setprio(0);                                      \
        }                                                                       \
    } while (0)

    STAGE_T(0, 0);
    STAGE_T(1, 1);
    asm volatile("s_waitcnt vmcnt(6)" ::: "memory");
    __builtin_amdgcn_s_barrier();
    asm volatile("" ::: "memory");

    for (int kt = 0; kt < NT; ++kt) {
        if (kt + 2 < NT) STAGE_T((kt + 2) % 3, kt + 2);
        COMPUTE_T(kt % 3);
        if (kt + 2 < NT) {
            asm volatile("s_waitcnt vmcnt(6)" ::: "memory");
            __builtin_amdgcn_s_barrier();
            asm volatile("" ::: "memory");
        } else if (kt + 2 == NT) {
            asm volatile("s_waitcnt vmcnt(0)" ::: "memory");
            __builtin_amdgcn_s_barrier();
            asm volatile("" ::: "memory");
        }
    }

#undef STAGE_T
#undef COMPUTE_T

    const float ds = ds_p[0];
    const int r0 = m0 + wm * 64 + (lane >> 4) * 4;
#pragma unroll
    for (int fm = 0; fm < 4; ++fm)
#pragma unroll
        for (int j = 0; j < 4; ++j) {
            const int row = r0 + fm * 16 + j;
            const float sc = ds * rs[row];
#pragma unroll
            for (int fn = 0; fn < 5; ++fn)
                outf[(size_t)row * H_DIM + (n0 + wn * 80 + fn * 16 + l15)] =
                    sc * acc[fm][fn][j];
        }
}

// ---------------------------------------------------------------------------
extern "C" void kernel_launch(void* const* d_in, const int* in_sizes, int n_in,
                              void* d_out, int out_size, void* d_ws, size_t ws_size,
                              hipStream_t stream) {
    const float* x   = (const float*)d_in[0];
    const int*   gp  = (const int*)d_in[1];
    const float* gs  = (const float*)d_in[2];
    const int*   upk = (const int*)d_in[3];
    const float* us  = (const float*)d_in[4];
    const int*   dp  = (const int*)d_in[5];
    const float* dsc = (const float*)d_in[6];
    const float* nw  = (const float*)d_in[7];
    float* out = (float*)d_out;

    char* ws = (char*)d_ws;
    __bf16* xb     = (__bf16*)ws;  ws += (size_t)NTOK * H_DIM * 2;
    __bf16* bgu    = (__bf16*)ws;  ws += (size_t)2 * I_DIM * H_DIM * 2;
    __bf16* wdb    = (__bf16*)ws;  ws += (size_t)H_DIM * I_DIM * 2;
    __bf16* hidden = (__bf16*)ws;  ws += (size_t)NTOK * I_DIM * 2;
    float*  rsbuf  = (float*)ws;   ws += (size_t)NTOK * 4;

    // merged prep
    prep_kernel<<<NB_CVT + NB_GU + NB_WD, 256, 0, stream>>>(
        x, xb, gp, upk, bgu, dp, nw, wdb);

    // gate+up fused GEMM + gating: 1728 blocks, 2 blocks/CU
    gemm_gu8<H_DIM><<<dim3((NTOK / 256) * (2 * I_DIM / 256)), 512, 0, stream>>>(
        xb, bgu, gs, us, hidden, 2 * I_DIM / 256);

    // RMSNorm scale
    rms_rs_kernel<<<NTOK, 256, 0, stream>>>(hidden, rsbuf);

    // down GEMM: 512 blocks (2 exact rounds)
    gemm_down_pipe<I_DIM><<<dim3((NTOK / 256) * (H_DIM / 160)), 512, 0, stream>>>(
        hidden, wdb, dsc, rsbuf, out, H_DIM / 160);
}

// Round 11
// 818.841 us; speedup vs baseline: 7.4069x; 7.4069x over previous
//
#include <hip/hip_runtime.h>
#include <cstdint>
#include <cstddef>

#define H_DIM 2560
#define I_DIM 6912
#define NTOK  8192   // B*S = 4*2048

typedef __attribute__((ext_vector_type(8))) __bf16 bf16x8;
typedef __attribute__((ext_vector_type(4))) float  f32x4;

// ---- async global->LDS, 16B per lane -------------------------------------
__device__ inline void gld16(void* lds, const void* g) {
    __builtin_amdgcn_global_load_lds(
        (__attribute__((address_space(1))) void*)(void*)g,
        (__attribute__((address_space(3))) void*)lds, 16, 0, 0);
}

// ---- merged prep: cvt_x | unpack gate+up | unpack down --------------------
#define NB_CVT 10240   // NTOK*H/8/256
#define NB_GU  17280   // 2*I*H/8/256
#define NB_WD  8640    // H*I/8/256

__global__ __launch_bounds__(256) void prep_kernel(
    const float* __restrict__ x, __bf16* __restrict__ xb,
    const int* __restrict__ gp, const int* __restrict__ up, __bf16* __restrict__ bgu,
    const int* __restrict__ dp, const float* __restrict__ nw, __bf16* __restrict__ wdb)
{
    const int bid = blockIdx.x;
    if (bid < NB_CVT) {
        int gid = bid * 256 + threadIdx.x;
        const float4* p = (const float4*)(x + (size_t)gid * 8);
        float4 v0 = p[0], v1 = p[1];
        bf16x8 o;
        o[0] = (__bf16)v0.x; o[1] = (__bf16)v0.y; o[2] = (__bf16)v0.z; o[3] = (__bf16)v0.w;
        o[4] = (__bf16)v1.x; o[5] = (__bf16)v1.y; o[6] = (__bf16)v1.z; o[7] = (__bf16)v1.w;
        *(bf16x8*)(xb + (size_t)gid * 8) = o;
    } else if (bid < NB_CVT + NB_GU) {
        const int per_row = H_DIM >> 3;
        const int half = I_DIM * per_row;
        int gid = (bid - NB_CVT) * 256 + threadIdx.x;
        const bool isup = gid >= half;
        const int g = isup ? gid - half : gid;
        const int* packed = isup ? up : gp;
        int i  = g / per_row;
        int k0 = (g % per_row) * 8;
        int blk = k0 >> 7, grp = (k0 >> 5) & 3, j0 = k0 & 31;
        int shift = 6 - 2 * grp;
        const int* p = packed + (size_t)i * (H_DIM >> 2) + blk * 32 + j0;
        int4 v0 = *(const int4*)p;
        int4 v1 = *(const int4*)(p + 4);
        int vals[8] = {v0.x, v0.y, v0.z, v0.w, v1.x, v1.y, v1.z, v1.w};
        bf16x8 o;
#pragma unroll
        for (int b = 0; b < 8; ++b)
            o[b] = (__bf16)(float)(((vals[b] >> shift) & 3) - 1);
        int dst = (i >> 4) * 32 + (i & 15) + (isup ? 16 : 0);
        *(bf16x8*)(bgu + (size_t)dst * H_DIM + k0) = o;
    } else {
        const int per_row = I_DIM >> 3;
        int gid = (bid - NB_CVT - NB_GU) * 256 + threadIdx.x;
        int i  = gid / per_row;
        int k0 = (gid % per_row) * 8;
        int blk = k0 >> 7, grp = (k0 >> 5) & 3, j0 = k0 & 31;
        int shift = 6 - 2 * grp;
        const int* p = dp + (size_t)i * (I_DIM >> 2) + blk * 32 + j0;
        int4 v0 = *(const int4*)p;
        int4 v1 = *(const int4*)(p + 4);
        int vals[8] = {v0.x, v0.y, v0.z, v0.w, v1.x, v1.y, v1.z, v1.w};
        bf16x8 o;
#pragma unroll
        for (int b = 0; b < 8; ++b) {
            float f = (float)(((vals[b] >> shift) & 3) - 1);
            o[b] = (__bf16)(f * nw[k0 + b]);
        }
        *(bf16x8*)(wdb + (size_t)i * I_DIM + k0) = o;
    }
}

// ---- per-token rsqrt(mean(hidden^2)+eps) ----------------------------------
__global__ __launch_bounds__(256) void rms_rs_kernel(const __bf16* __restrict__ hidden,
                                                     float* __restrict__ rs) {
    const int tk = blockIdx.x;
    const __bf16* row = hidden + (size_t)tk * I_DIM;
    float s = 0.f;
    for (int idx = threadIdx.x; idx < I_DIM / 8; idx += 256) {
        bf16x8 v = *(const bf16x8*)&row[idx * 8];
#pragma unroll
        for (int j = 0; j < 8; ++j) { float f = (float)v[j]; s += f * f; }
    }
#pragma unroll
    for (int off = 32; off; off >>= 1) s += __shfl_down(s, off, 64);
    __shared__ float wsum[4];
    if ((threadIdx.x & 63) == 0) wsum[threadIdx.x >> 6] = s;
    __syncthreads();
    if (threadIdx.x == 0) {
        float tot = wsum[0] + wsum[1] + wsum[2] + wsum[3];
        rs[tk] = rsqrtf(tot / (float)I_DIM + 1e-6f);
    }
}

// ===========================================================================
// R11 gate+up GEMM: BM=BN=256, BK=32, LDS 64 KiB. __launch_bounds__(512,2)
// (R10's (512,4) forced a VGPR cap -> accumulator spill, 14GB scratch).
// With natural VGPR (~112 <= 128) HW can co-schedule 2 blocks/CU.
// 2 phases/tile {nh0, nh1}; A+B row-pair 128B lines, R4-proven XOR swizzle.
// Depth-2 prefetch, counted vmcnt(2). Ledger as R10 (correctness verified).
// ===========================================================================
template<int KDIM>
__global__ __launch_bounds__(512, 2) void gemm_gu8(
    const __bf16* __restrict__ A,
    const __bf16* __restrict__ B,
    const float* __restrict__ gs_p,
    const float* __restrict__ us_p,
    __bf16* __restrict__ hidden,
    int nby)
{
    constexpr int KB = KDIM * 2;
    constexpr int NT = KDIM / 32;
    __shared__ __align__(16) char smem[65536];   // 2 buf x {A 16KB | B 16KB}

    const int nwg = (int)gridDim.x;
    const int q = nwg >> 3;
    const int id = (int)blockIdx.x;
    const int wg = (id & 7) * q + (id >> 3);
    const int bx = wg / nby, by = wg % nby;
    const int m0 = bx * 256, n0 = by * 256;

    const int t = (int)threadIdx.x;
    const int lane = t & 63;
    const int wid = t >> 6;
    const int wm = wid >> 2, wn = wid & 3;
    const int l15 = lane & 15, s8 = lane >> 4;

    const int qa  = (t & 7) ^ ((t >> 3) & 7);
    const int rA2 = ((t >> 3) << 1) + (qa >> 2);
    const int cb  = (qa & 3) * 16;
    const char* gA0 = (const char*)A + (size_t)(m0 + rA2) * KB + cb;
    const char* gA1 = (const char*)A + (size_t)(m0 + 128 + rA2) * KB + cb;
    const char* gBp0 = (const char*)B + (size_t)(n0 + rA2) * KB + cb;
    const char* gBp1 = (const char*)B + (size_t)(n0 + 128 + rA2) * KB + cb;
    char* ldst = smem + t * 16;

    const int rswz  = ((((l15 & 1) << 2) | s8) ^ ((l15 >> 1) & 7)) << 4;
    const int abase = (wm * 64 + (l15 >> 1)) * 128 + rswz;
    const int bbase = (wn * 32 + (l15 >> 1)) * 128 + rswz;

    f32x4 acc[8][4];
#pragma unroll
    for (int f = 0; f < 8; ++f)
#pragma unroll
        for (int n = 0; n < 4; ++n) acc[f][n] = (f32x4){0, 0, 0, 0};

#define STG_A(d, kt) do {                                                  \
        gld16(ldst + (d) * 32768,        gA0 + (size_t)(kt) * 64);         \
        gld16(ldst + (d) * 32768 + 8192, gA1 + (size_t)(kt) * 64);         \
    } while (0)
#define STG_B(d, kt) do {                                                  \
        gld16(ldst + (d) * 32768 + 16384,        gBp0 + (size_t)(kt) * 64);\
        gld16(ldst + (d) * 32768 + 16384 + 8192, gBp1 + (size_t)(kt) * 64);\
    } while (0)
#define LOAD_A(d) do { _Pragma("unroll")                                   \
        for (int _f = 0; _f < 8; ++_f)                                     \
            a[_f] = *(const bf16x8*)(smem + (d) * 32768 +                  \
                                     _f * 1024 + abase); } while (0)
#define LOAD_B(d, nh) do {                                                 \
        b0 = *(const bf16x8*)(smem + (d) * 32768 + 16384 + (nh) * 2048 +   \
                              bbase);                                      \
        b1 = *(const bf16x8*)(smem + (d) * 32768 + 16384 + (nh) * 2048 +   \
                              bbase + 1024); } while (0)
#define MFMA16(nh) do { __builtin_amdgcn_s_setprio(1); _Pragma("unroll")   \
        for (int _f = 0; _f < 8; ++_f) {                                   \
            acc[_f][(nh) * 2] = __builtin_amdgcn_mfma_f32_16x16x32_bf16(   \
                a[_f], b0, acc[_f][(nh) * 2], 0, 0, 0);                    \
            acc[_f][(nh) * 2 + 1] = __builtin_amdgcn_mfma_f32_16x16x32_bf16(\
                a[_f], b1, acc[_f][(nh) * 2 + 1], 0, 0, 0); }              \
        __builtin_amdgcn_s_setprio(0); } while (0)
#define BAR() do { asm volatile("" ::: "memory");                          \
        __builtin_amdgcn_s_barrier();                                      \
        asm volatile("" ::: "memory"); } while (0)

    STG_A(0, 0); STG_B(0, 0); STG_A(1, 1);
    asm volatile("s_waitcnt vmcnt(2)" ::: "memory");
    BAR();

    bf16x8 a[8], b0, b1;
    for (int kt = 0; kt < NT; ++kt) {
        const int d = kt & 1;
        // P1 (nh0): a-frags + b(nh0); stage (kt+1).B into d^1
        LOAD_A(d); LOAD_B(d, 0);
        if (kt + 1 < NT) STG_B(d ^ 1, kt + 1);
        MFMA16(0); BAR();
        // P2 (nh1): b(nh1); stage (kt+2).A into d; counted tile-boundary wait
        LOAD_B(d, 1);
        if (kt + 2 < NT) {
            STG_A(d, kt + 2);
            asm volatile("s_waitcnt vmcnt(2)" ::: "memory");
        } else if (kt + 1 < NT) {
            asm volatile("s_waitcnt vmcnt(0)" ::: "memory");
        }
        MFMA16(1); BAR();
    }

#undef STG_A
#undef STG_B
#undef LOAD_A
#undef LOAD_B
#undef MFMA16
#undef BAR

    const float comb = gs_p[0] * gs_p[0] * us_p[0];
    const int r0 = m0 + wm * 128 + s8 * 4;
#pragma unroll
    for (int f = 0; f < 8; ++f)
#pragma unroll
        for (int p = 0; p < 2; ++p)
#pragma unroll
            for (int j = 0; j < 4; ++j) {
                float g = acc[f][2 * p][j];
                float u = acc[f][2 * p + 1][j];
                float r = fmaxf(g, 0.f);
                hidden[(size_t)(r0 + f * 16 + j) * I_DIM +
                       ((by * 8 + wn * 2 + p) * 16 + l15)] = (__bf16)(comb * r * r * u);
            }
}

// ===========================================================================
// Down GEMM (R8-proven): BM=256, BN=160, BK=64, grid 512 = 2 exact rounds,
// triple-buffer depth-2, vmcnt(6), T2 swizzle, T5 setprio.
// ===========================================================================
template<int KDIM>
__global__ __launch_bounds__(512) void gemm_down_pipe(
    const __bf16* __restrict__ A,
    const __bf16* __restrict__ B,
    const float* __restrict__ ds_p,
    const float* __restrict__ rs,
    float* __restrict__ outf,
    int nby)
{
    constexpr int BM = 256, BN = 160, BK = 64;
    constexpr int NT = KDIM / BK;
    constexpr int SLOTB = (BM + BN) * BK * 2;
    __shared__ __align__(16) char smem[3 * SLOTB];

    const int nwg = (int)gridDim.x;
    const int q = nwg >> 3;
    const int id = (int)blockIdx.x;
    const int wg = (id & 7) * q + (id >> 3);
    const int bx = wg / nby;
    const int by = wg % nby;

    const int m0 = bx * BM;
    const int n0 = by * BN;
    const int t  = (int)threadIdx.x;
    const int lane = t & 63;
    const int wm = (t >> 6) >> 1;
    const int wn = (t >> 6) & 1;

    const int srow = t >> 3;
    const int scol = ((t & 7) * 16) ^ ((srow & 7) << 4);
    const char* gA = (const char*)A + (size_t)(m0 + srow) * (KDIM * 2) + scol;
    const char* gB = (const char*)B + (size_t)(n0 + srow) * (KDIM * 2) + scol;
    char* lbase = smem + t * 16;

    const int l15 = lane & 15;
    const int xv  = (l15 & 7) << 4;
    const int colx[2] = { (((lane >> 4) * 16) ^ xv), ((64 + (lane >> 4) * 16) ^ xv) };

    f32x4 acc[4][5];
#pragma unroll
    for (int a = 0; a < 4; ++a)
#pragma unroll
        for (int b = 0; b < 5; ++b) acc[a][b] = (f32x4){0, 0, 0, 0};

#define STAGE_T(s, kt) do {                                                     \
        char* _ls = lbase + (s) * SLOTB;                                        \
        const char* _ga = gA + (kt) * (BK * 2);                                 \
        _Pragma("unroll")                                                       \
        for (int _i = 0; _i < 4; ++_i)                                          \
            gld16(_ls + _i * 8192, _ga + (size_t)_i * 64 * (KDIM * 2));         \
        const char* _gb = gB + (kt) * (BK * 2);                                 \
        char* _lb = _ls + BM * BK * 2;                                          \
        _Pragma("unroll")                                                       \
        for (int _i = 0; _i < 2; ++_i)                                          \
            gld16(_lb + _i * 8192, _gb + (size_t)_i * 64 * (KDIM * 2));         \
        if (t < 256)                                                            \
            gld16(_lb + 2 * 8192, _gb + (size_t)2 * 64 * (KDIM * 2));           \
    } while (0)

#define COMPUTE_T(s) do {                                                       \
        const char* _sa = smem + (s) * SLOTB;                                   \
        const char* _sb = _sa + BM * BK * 2;                                    \
        _Pragma("unroll")                                                       \
        for (int _kk = 0; _kk < 2; ++_kk) {                                     \
            bf16x8 _a[4], _b[5];                                                \
            _Pragma("unroll")                                                   \
            for (int _f = 0; _f < 4; ++_f)                                      \
                _a[_f] = *(const bf16x8*)(_sa + (wm * 64 + _f * 16 + l15) * 128 + colx[_kk]); \
            _Pragma("unroll")                                                   \
            for (int _f = 0; _f < 5; ++_f)                                      \
                _b[_f] = *(const bf16x8*)(_sb + (wn * 80 + _f * 16 + l15) * 128 + colx[_kk]); \
            __builtin_amdgcn_s_setprio(1);                                      \
            _Pragma("unroll")                                                   \
            for (int _fm = 0; _fm < 4; ++_fm)                                   \
                _Pragma("unroll")                                               \
                for (int _fn = 0; _fn < 5; ++_fn)                               \
                    acc[_fm][_fn] = __builtin_amdgcn_mfma_f32_16x16x32_bf16(    \
                        _a[_fm], _b[_fn], acc[_fm][_fn], 0, 0, 0);              \
            __builtin_amdgcn_s_setprio(0);                                      \
        }                                                                       \
    } while (0)

    STAGE_T(0, 0);
    STAGE_T(1, 1);
    asm volatile("s_waitcnt vmcnt(6)" ::: "memory");
    __builtin_amdgcn_s_barrier();
    asm volatile("" ::: "memory");

    for (int kt = 0; kt < NT; ++kt) {
        if (kt + 2 < NT) STAGE_T((kt + 2) % 3, kt + 2);
        COMPUTE_T(kt % 3);
        if (kt + 2 < NT) {
            asm volatile("s_waitcnt vmcnt(6)" ::: "memory");
            __builtin_amdgcn_s_barrier();
            asm volatile("" ::: "memory");
        } else if (kt + 2 == NT) {
            asm volatile("s_waitcnt vmcnt(0)" ::: "memory");
            __builtin_amdgcn_s_barrier();
            asm volatile("" ::: "memory");
        }
    }

#undef STAGE_T
#undef COMPUTE_T

    const float ds = ds_p[0];
    const int r0 = m0 + wm * 64 + (lane >> 4) * 4;
#pragma unroll
    for (int fm = 0; fm < 4; ++fm)
#pragma unroll
        for (int j = 0; j < 4; ++j) {
            const int row = r0 + fm * 16 + j;
            const float sc = ds * rs[row];
#pragma unroll
            for (int fn = 0; fn < 5; ++fn)
                outf[(size_t)row * H_DIM + (n0 + wn * 80 + fn * 16 + l15)] =
                    sc * acc[fm][fn][j];
        }
}

// ---------------------------------------------------------------------------
extern "C" void kernel_launch(void* const* d_in, const int* in_sizes, int n_in,
                              void* d_out, int out_size, void* d_ws, size_t ws_size,
                              hipStream_t stream) {
    const float* x   = (const float*)d_in[0];
    const int*   gp  = (const int*)d_in[1];
    const float* gs  = (const float*)d_in[2];
    const int*   upk = (const int*)d_in[3];
    const float* us  = (const float*)d_in[4];
    const int*   dp  = (const int*)d_in[5];
    const float* dsc = (const float*)d_in[6];
    const float* nw  = (const float*)d_in[7];
    float* out = (float*)d_out;

    char* ws = (char*)d_ws;
    __bf16* xb     = (__bf16*)ws;  ws += (size_t)NTOK * H_DIM * 2;
    __bf16* bgu    = (__bf16*)ws;  ws += (size_t)2 * I_DIM * H_DIM * 2;
    __bf16* wdb    = (__bf16*)ws;  ws += (size_t)H_DIM * I_DIM * 2;
    __bf16* hidden = (__bf16*)ws;  ws += (size_t)NTOK * I_DIM * 2;
    float*  rsbuf  = (float*)ws;   ws += (size_t)NTOK * 4;

    // merged prep
    prep_kernel<<<NB_CVT + NB_GU + NB_WD, 256, 0, stream>>>(
        x, xb, gp, upk, bgu, dp, nw, wdb);

    // gate+up fused GEMM + gating: 1728 blocks
    gemm_gu8<H_DIM><<<dim3((NTOK / 256) * (2 * I_DIM / 256)), 512, 0, stream>>>(
        xb, bgu, gs, us, hidden, 2 * I_DIM / 256);

    // RMSNorm scale
    rms_rs_kernel<<<NTOK, 256, 0, stream>>>(hidden, rsbuf);

    // down GEMM: 512 blocks (2 exact rounds)
    gemm_down_pipe<I_DIM><<<dim3((NTOK / 256) * (H_DIM / 160)), 512, 0, stream>>>(
        hidden, wdb, dsc, rsbuf, out, H_DIM / 160);
}

// Round 12
// 756.287 us; speedup vs baseline: 8.0195x; 1.0827x over previous
//
#include <hip/hip_runtime.h>
#include <cstdint>
#include <cstddef>

#define H_DIM 2560
#define I_DIM 6912
#define NTOK  8192   // B*S = 4*2048

typedef __attribute__((ext_vector_type(8))) __bf16 bf16x8;
typedef __attribute__((ext_vector_type(4))) float  f32x4;

// ---- async global->LDS, 16B per lane -------------------------------------
__device__ inline void gld16(void* lds, const void* g) {
    __builtin_amdgcn_global_load_lds(
        (__attribute__((address_space(1))) void*)(void*)g,
        (__attribute__((address_space(3))) void*)lds, 16, 0, 0);
}

// ---- merged prep: cvt_x | unpack gate+up | unpack down --------------------
#define NB_CVT 10240   // NTOK*H/8/256
#define NB_GU  17280   // 2*I*H/8/256
#define NB_WD  8640    // H*I/8/256

__global__ __launch_bounds__(256) void prep_kernel(
    const float* __restrict__ x, __bf16* __restrict__ xb,
    const int* __restrict__ gp, const int* __restrict__ up, __bf16* __restrict__ bgu,
    const int* __restrict__ dp, const float* __restrict__ nw, __bf16* __restrict__ wdb)
{
    const int bid = blockIdx.x;
    if (bid < NB_CVT) {
        int gid = bid * 256 + threadIdx.x;
        const float4* p = (const float4*)(x + (size_t)gid * 8);
        float4 v0 = p[0], v1 = p[1];
        bf16x8 o;
        o[0] = (__bf16)v0.x; o[1] = (__bf16)v0.y; o[2] = (__bf16)v0.z; o[3] = (__bf16)v0.w;
        o[4] = (__bf16)v1.x; o[5] = (__bf16)v1.y; o[6] = (__bf16)v1.z; o[7] = (__bf16)v1.w;
        *(bf16x8*)(xb + (size_t)gid * 8) = o;
    } else if (bid < NB_CVT + NB_GU) {
        const int per_row = H_DIM >> 3;
        const int half = I_DIM * per_row;
        int gid = (bid - NB_CVT) * 256 + threadIdx.x;
        const bool isup = gid >= half;
        const int g = isup ? gid - half : gid;
        const int* packed = isup ? up : gp;
        int i  = g / per_row;
        int k0 = (g % per_row) * 8;
        int blk = k0 >> 7, grp = (k0 >> 5) & 3, j0 = k0 & 31;
        int shift = 6 - 2 * grp;
        const int* p = packed + (size_t)i * (H_DIM >> 2) + blk * 32 + j0;
        int4 v0 = *(const int4*)p;
        int4 v1 = *(const int4*)(p + 4);
        int vals[8] = {v0.x, v0.y, v0.z, v0.w, v1.x, v1.y, v1.z, v1.w};
        bf16x8 o;
#pragma unroll
        for (int b = 0; b < 8; ++b)
            o[b] = (__bf16)(float)(((vals[b] >> shift) & 3) - 1);
        int dst = (i >> 4) * 32 + (i & 15) + (isup ? 16 : 0);
        *(bf16x8*)(bgu + (size_t)dst * H_DIM + k0) = o;
    } else {
        const int per_row = I_DIM >> 3;
        int gid = (bid - NB_CVT - NB_GU) * 256 + threadIdx.x;
        int i  = gid / per_row;
        int k0 = (gid % per_row) * 8;
        int blk = k0 >> 7, grp = (k0 >> 5) & 3, j0 = k0 & 31;
        int shift = 6 - 2 * grp;
        const int* p = dp + (size_t)i * (I_DIM >> 2) + blk * 32 + j0;
        int4 v0 = *(const int4*)p;
        int4 v1 = *(const int4*)(p + 4);
        int vals[8] = {v0.x, v0.y, v0.z, v0.w, v1.x, v1.y, v1.z, v1.w};
        bf16x8 o;
#pragma unroll
        for (int b = 0; b < 8; ++b) {
            float f = (float)(((vals[b] >> shift) & 3) - 1);
            o[b] = (__bf16)(f * nw[k0 + b]);
        }
        *(bf16x8*)(wdb + (size_t)i * I_DIM + k0) = o;
    }
}

// ---- per-token rsqrt(mean(hidden^2)+eps) ----------------------------------
__global__ __launch_bounds__(256) void rms_rs_kernel(const __bf16* __restrict__ hidden,
                                                     float* __restrict__ rs) {
    const int tk = blockIdx.x;
    const __bf16* row = hidden + (size_t)tk * I_DIM;
    float s = 0.f;
    for (int idx = threadIdx.x; idx < I_DIM / 8; idx += 256) {
        bf16x8 v = *(const bf16x8*)&row[idx * 8];
#pragma unroll
        for (int j = 0; j < 8; ++j) { float f = (float)v[j]; s += f * f; }
    }
#pragma unroll
    for (int off = 32; off; off >>= 1) s += __shfl_down(s, off, 64);
    __shared__ float wsum[4];
    if ((threadIdx.x & 63) == 0) wsum[threadIdx.x >> 6] = s;
    __syncthreads();
    if (threadIdx.x == 0) {
        float tot = wsum[0] + wsum[1] + wsum[2] + wsum[3];
        rs[tk] = rsqrtf(tot / (float)I_DIM + 1e-6f);
    }
}

// ===========================================================================
// R12 gate+up GEMM: R9 structure (BK=64, LDS 128 KiB, depth-2, vmcnt(4))
// with phase-PAIR fusion: 2 phases/tile {kk0, kk1}, each phase =
// {8 A-reads + 4 B-reads; 4 stage-issues; 32-MFMA cluster; barrier}.
// Drain semantics identical to R9 (issue-order queue walked: vmcnt(4) at
// kt.PhB drains exactly tile kt+1's four quarter-stages). Barriers 4->2/tile.
// ===========================================================================
template<int KDIM>
__global__ __launch_bounds__(512, 2) void gemm_gu8(
    const __bf16* __restrict__ A,
    const __bf16* __restrict__ B,
    const float* __restrict__ gs_p,
    const float* __restrict__ us_p,
    __bf16* __restrict__ hidden,
    int nby)
{
    constexpr int KB = KDIM * 2;
    constexpr int NT = KDIM / 64;
    __shared__ __align__(16) char smem[131072];

    const int nwg = (int)gridDim.x;
    const int q = nwg >> 3;
    const int id = (int)blockIdx.x;
    const int wg = (id & 7) * q + (id >> 3);
    const int bx = wg / nby, by = wg % nby;
    const int m0 = bx * 256, n0 = by * 256;

    const int t = (int)threadIdx.x;
    const int lane = t & 63;
    const int wid = t >> 6;
    const int wm = wid >> 2, wn = wid & 3;
    const int l15 = lane & 15, s8 = lane >> 4;

    const int qa  = (t & 7) ^ ((t >> 3) & 7);
    const int rA2 = ((t >> 3) << 1) + (qa >> 2);
    const char* gA0 = (const char*)A + (size_t)(m0 + rA2) * KB + (qa & 3) * 16;
    const char* gA1 = (const char*)A + (size_t)(m0 + 128 + rA2) * KB + (qa & 3) * 16;
    const int sr0 = t >> 3, sr1 = 64 + (t >> 3);
    const int br0 = ((sr0 >> 5) << 6) + (sr0 & 31);
    const int br1 = ((sr1 >> 5) << 6) + (sr1 & 31);
    const char* gB0 = (const char*)B + (size_t)(n0 + br0) * KB + qa * 16;
    const char* gB1 = (const char*)B + (size_t)(n0 + br1) * KB + qa * 16;
    char* ldst = smem + t * 16;

    const int aoff = (wm * 64 + (l15 >> 1)) * 128 +
                     (((((l15 & 1) << 2) | s8) ^ ((l15 >> 1) & 7)) << 4);
    const int boff = (wn * 32 + l15) * 128;
    const int bco0 = ((s8) ^ (l15 & 7)) << 4;
    const int bco1 = ((4 | s8) ^ (l15 & 7)) << 4;

    f32x4 acc[8][4];
#pragma unroll
    for (int f = 0; f < 8; ++f)
#pragma unroll
        for (int n = 0; n < 4; ++n) acc[f][n] = (f32x4){0, 0, 0, 0};

#define STG_A(d, kt, kk) do {                                              \
        size_t _oA = (size_t)(kt) * 128 + (kk) * 64;                       \
        gld16(ldst + (d) * 65536 + (kk) * 16384,        gA0 + _oA);        \
        gld16(ldst + (d) * 65536 + (kk) * 16384 + 8192, gA1 + _oA);        \
    } while (0)
#define STG_B(d, kt, nh) do {                                              \
        size_t _oB = (size_t)(nh) * 32 * KB + (size_t)(kt) * 128;          \
        gld16(ldst + (d) * 65536 + 32768 + (nh) * 16384,        gB0 + _oB);\
        gld16(ldst + (d) * 65536 + 32768 + (nh) * 16384 + 8192, gB1 + _oB);\
    } while (0)
#define LOAD_A(d, kk) do { _Pragma("unroll")                               \
        for (int _f = 0; _f < 8; ++_f)                                     \
            a[_f] = *(const bf16x8*)(smem + (d) * 65536 + (kk) * 16384 +   \
                                     _f * 1024 + aoff); } while (0)
#define LOAD_B4(d, bc) do {                                                \
        b0 = *(const bf16x8*)(smem + (d) * 65536 + 32768 +                 \
                              boff + (bc));                                \
        b1 = *(const bf16x8*)(smem + (d) * 65536 + 32768 +                 \
                              boff + (bc) + 2048);                         \
        b2 = *(const bf16x8*)(smem + (d) * 65536 + 32768 + 16384 +         \
                              boff + (bc));                                \
        b3 = *(const bf16x8*)(smem + (d) * 65536 + 32768 + 16384 +         \
                              boff + (bc) + 2048); } while (0)
#define MFMA32() do { __builtin_amdgcn_s_setprio(1); _Pragma("unroll")     \
        for (int _f = 0; _f < 8; ++_f) {                                   \
            acc[_f][0] = __builtin_amdgcn_mfma_f32_16x16x32_bf16(          \
                a[_f], b0, acc[_f][0], 0, 0, 0);                           \
            acc[_f][1] = __builtin_amdgcn_mfma_f32_16x16x32_bf16(          \
                a[_f], b1, acc[_f][1], 0, 0, 0);                           \
            acc[_f][2] = __builtin_amdgcn_mfma_f32_16x16x32_bf16(          \
                a[_f], b2, acc[_f][2], 0, 0, 0);                           \
            acc[_f][3] = __builtin_amdgcn_mfma_f32_16x16x32_bf16(          \
                a[_f], b3, acc[_f][3], 0, 0, 0); }                         \
        __builtin_amdgcn_s_setprio(0); } while (0)
#define BAR() do { asm volatile("" ::: "memory");                          \
        __builtin_amdgcn_s_barrier();                                      \
        asm volatile("" ::: "memory"); } while (0)

    // prologue: tile0 full + tile1 {Akk0, Bnh0}; drain tile0 (vmcnt(4))
    STG_A(0, 0, 0); STG_A(0, 0, 1); STG_B(0, 0, 0); STG_B(0, 0, 1);
    STG_A(1, 1, 0); STG_B(1, 1, 0);
    asm volatile("s_waitcnt vmcnt(4)" ::: "memory");
    BAR();

    bf16x8 a[8], b0, b1, b2, b3;
    for (int kt = 0; kt < NT; ++kt) {
        const int d = kt & 1;
        // PhA (kk0): stage (kt+1).{Akk1, Bnh1} into d^1
        LOAD_A(d, 0); LOAD_B4(d, bco0);
        if (kt + 1 < NT) { STG_A(d ^ 1, kt + 1, 1); STG_B(d ^ 1, kt + 1, 1); }
        MFMA32(); BAR();
        // PhB (kk1): stage (kt+2).{Akk0, Bnh0} into d; counted tile wait
        LOAD_A(d, 1); LOAD_B4(d, bco1);
        if (kt + 2 < NT) {
            STG_A(d, kt + 2, 0); STG_B(d, kt + 2, 0);
            asm volatile("s_waitcnt vmcnt(4)" ::: "memory");
        } else {
            asm volatile("s_waitcnt vmcnt(0)" ::: "memory");
        }
        MFMA32(); BAR();
    }

#undef STG_A
#undef STG_B
#undef LOAD_A
#undef LOAD_B4
#undef MFMA32
#undef BAR

    const float comb = gs_p[0] * gs_p[0] * us_p[0];
    const int r0 = m0 + wm * 128 + s8 * 4;
#pragma unroll
    for (int f = 0; f < 8; ++f)
#pragma unroll
        for (int p = 0; p < 2; ++p)
#pragma unroll
            for (int j = 0; j < 4; ++j) {
                float g = acc[f][2 * p][j];
                float u = acc[f][2 * p + 1][j];
                float r = fmaxf(g, 0.f);
                hidden[(size_t)(r0 + f * 16 + j) * I_DIM +
                       ((by * 8 + wn * 2 + p) * 16 + l15)] = (__bf16)(comb * r * r * u);
            }
}

// ===========================================================================
// Down GEMM (R8-proven): BM=256, BN=160, BK=64, grid 512 = 2 exact rounds,
// triple-buffer depth-2, vmcnt(6), T2 swizzle, T5 setprio.
// ===========================================================================
template<int KDIM>
__global__ __launch_bounds__(512) void gemm_down_pipe(
    const __bf16* __restrict__ A,
    const __bf16* __restrict__ B,
    const float* __restrict__ ds_p,
    const float* __restrict__ rs,
    float* __restrict__ outf,
    int nby)
{
    constexpr int BM = 256, BN = 160, BK = 64;
    constexpr int NT = KDIM / BK;
    constexpr int SLOTB = (BM + BN) * BK * 2;
    __shared__ __align__(16) char smem[3 * SLOTB];

    const int nwg = (int)gridDim.x;
    const int q = nwg >> 3;
    const int id = (int)blockIdx.x;
    const int wg = (id & 7) * q + (id >> 3);
    const int bx = wg / nby;
    const int by = wg % nby;

    const int m0 = bx * BM;
    const int n0 = by * BN;
    const int t  = (int)threadIdx.x;
    const int lane = t & 63;
    const int wm = (t >> 6) >> 1;
    const int wn = (t >> 6) & 1;

    const int srow = t >> 3;
    const int scol = ((t & 7) * 16) ^ ((srow & 7) << 4);
    const char* gA = (const char*)A + (size_t)(m0 + srow) * (KDIM * 2) + scol;
    const char* gB = (const char*)B + (size_t)(n0 + srow) * (KDIM * 2) + scol;
    char* lbase = smem + t * 16;

    const int l15 = lane & 15;
    const int xv  = (l15 & 7) << 4;
    const int colx[2] = { (((lane >> 4) * 16) ^ xv), ((64 + (lane >> 4) * 16) ^ xv) };

    f32x4 acc[4][5];
#pragma unroll
    for (int a = 0; a < 4; ++a)
#pragma unroll
        for (int b = 0; b < 5; ++b) acc[a][b] = (f32x4){0, 0, 0, 0};

#define STAGE_T(s, kt) do {                                                     \
        char* _ls = lbase + (s) * SLOTB;                                        \
        const char* _ga = gA + (kt) * (BK * 2);                                 \
        _Pragma("unroll")                                                       \
        for (int _i = 0; _i < 4; ++_i)                                          \
            gld16(_ls + _i * 8192, _ga + (size_t)_i * 64 * (KDIM * 2));         \
        const char* _gb = gB + (kt) * (BK * 2);                                 \
        char* _lb = _ls + BM * BK * 2;                                          \
        _Pragma("unroll")                                                       \
        for (int _i = 0; _i < 2; ++_i)                                          \
            gld16(_lb + _i * 8192, _gb + (size_t)_i * 64 * (KDIM * 2));         \
        if (t < 256)                                                            \
            gld16(_lb + 2 * 8192, _gb + (size_t)2 * 64 * (KDIM * 2));           \
    } while (0)

#define COMPUTE_T(s) do {                                                       \
        const char* _sa = smem + (s) * SLOTB;                                   \
        const char* _sb = _sa + BM * BK * 2;                                    \
        _Pragma("unroll")                                                       \
        for (int _kk = 0; _kk < 2; ++_kk) {                                     \
            bf16x8 _a[4], _b[5];                                                \
            _Pragma("unroll")                                                   \
            for (int _f = 0; _f < 4; ++_f)                                      \
                _a[_f] = *(const bf16x8*)(_sa + (wm * 64 + _f * 16 + l15) * 128 + colx[_kk]); \
            _Pragma("unroll")                                                   \
            for (int _f = 0; _f < 5; ++_f)                                      \
                _b[_f] = *(const bf16x8*)(_sb + (wn * 80 + _f * 16 + l15) * 128 + colx[_kk]); \
            __builtin_amdgcn_s_setprio(1);                                      \
            _Pragma("unroll")                                                   \
            for (int _fm = 0; _fm < 4; ++_fm)                                   \
                _Pragma("unroll")                                               \
                for (int _fn = 0; _fn < 5; ++_fn)                               \
                    acc[_fm][_fn] = __builtin_amdgcn_mfma_f32_16x16x32_bf16(    \
                        _a[_fm], _b[_fn], acc[_fm][_fn], 0, 0, 0);              \
            __builtin_amdgcn_s_setprio(0);                                      \
        }                                                                       \
    } while (0)

    STAGE_T(0, 0);
    STAGE_T(1, 1);
    asm volatile("s_waitcnt vmcnt(6)" ::: "memory");
    __builtin_amdgcn_s_barrier();
    asm volatile("" ::: "memory");

    for (int kt = 0; kt < NT; ++kt) {
        if (kt + 2 < NT) STAGE_T((kt + 2) % 3, kt + 2);
        COMPUTE_T(kt % 3);
        if (kt + 2 < NT) {
            asm volatile("s_waitcnt vmcnt(6)" ::: "memory");
            __builtin_amdgcn_s_barrier();
            asm volatile("" ::: "memory");
        } else if (kt + 2 == NT) {
            asm volatile("s_waitcnt vmcnt(0)" ::: "memory");
            __builtin_amdgcn_s_barrier();
            asm volatile("" ::: "memory");
        }
    }

#undef STAGE_T
#undef COMPUTE_T

    const float ds = ds_p[0];
    const int r0 = m0 + wm * 64 + (lane >> 4) * 4;
#pragma unroll
    for (int fm = 0; fm < 4; ++fm)
#pragma unroll
        for (int j = 0; j < 4; ++j) {
            const int row = r0 + fm * 16 + j;
            const float sc = ds * rs[row];
#pragma unroll
            for (int fn = 0; fn < 5; ++fn)
                outf[(size_t)row * H_DIM + (n0 + wn * 80 + fn * 16 + l15)] =
                    sc * acc[fm][fn][j];
        }
}

// ---------------------------------------------------------------------------
extern "C" void kernel_launch(void* const* d_in, const int* in_sizes, int n_in,
                              void* d_out, int out_size, void* d_ws, size_t ws_size,
                              hipStream_t stream) {
    const float* x   = (const float*)d_in[0];
    const int*   gp  = (const int*)d_in[1];
    const float* gs  = (const float*)d_in[2];
    const int*   upk = (const int*)d_in[3];
    const float* us  = (const float*)d_in[4];
    const int*   dp  = (const int*)d_in[5];
    const float* dsc = (const float*)d_in[6];
    const float* nw  = (const float*)d_in[7];
    float* out = (float*)d_out;

    char* ws = (char*)d_ws;
    __bf16* xb     = (__bf16*)ws;  ws += (size_t)NTOK * H_DIM * 2;
    __bf16* bgu    = (__bf16*)ws;  ws += (size_t)2 * I_DIM * H_DIM * 2;
    __bf16* wdb    = (__bf16*)ws;  ws += (size_t)H_DIM * I_DIM * 2;
    __bf16* hidden = (__bf16*)ws;  ws += (size_t)NTOK * I_DIM * 2;
    float*  rsbuf  = (float*)ws;   ws += (size_t)NTOK * 4;

    // merged prep
    prep_kernel<<<NB_CVT + NB_GU + NB_WD, 256, 0, stream>>>(
        x, xb, gp, upk, bgu, dp, nw, wdb);

    // gate+up fused GEMM + gating: 1728 blocks
    gemm_gu8<H_DIM><<<dim3((NTOK / 256) * (2 * I_DIM / 256)), 512, 0, stream>>>(
        xb, bgu, gs, us, hidden, 2 * I_DIM / 256);

    // RMSNorm scale
    rms_rs_kernel<<<NTOK, 256, 0, stream>>>(hidden, rsbuf);

    // down GEMM: 512 blocks (2 exact rounds)
    gemm_down_pipe<I_DIM><<<dim3((NTOK / 256) * (H_DIM / 160)), 512, 0, stream>>>(
        hidden, wdb, dsc, rsbuf, out, H_DIM / 160);
}